// Round 5
// baseline (3725.283 us; speedup 1.0000x reference)
//
#include <hip/hip_runtime.h>
#include <stdint.h>
#include <stddef.h>

// ---------------------------------------------------------------------------
// Discriminator: embedding [64,512] -> GRU(512->1024, 512 steps) -> FC(1024->2)
//   k1 embed_k : gather emb rows -> X fp16 [S*B, 512]   (row = s*64+b)
//   k2 wconv   : w_ih fp32 -> fp16
//   k3 gemm_gx : GX = X @ w_ih^T + b_ih  -> fp16 [S*B, 3072]  (MFMA 128x128 tile)
//   k4 gru_rec : persistent 256-WG kernel, 4 batch-groups x 64 unit-groups,
//                w_hh slice LDS-resident fp16. Cross-WG h exchange: packed
//                {tag16,h16} dwords at the coherence point (sc0sc1, self-
//                validating) + per-producer FLAG gating the single bulk load
//                (flags make polling cheap; tags make it correct).
//   k5 fc_k    : logits = h_last @ fc_w^T + fc_b -> d_out fp32 [64,2]
// ---------------------------------------------------------------------------

typedef _Float16 f16;
typedef _Float16 f16x4 __attribute__((ext_vector_type(4)));
typedef _Float16 f16x8 __attribute__((ext_vector_type(8)));
typedef float f32x4 __attribute__((ext_vector_type(4)));
typedef unsigned int u32;
typedef u32 u32x4 __attribute__((ext_vector_type(4)));

#define NB 64      // batch
#define NS 512     // seq len
#define NE 512     // embedding dim
#define NH 1024    // hidden
#define G3 3072    // 3*NH

static __device__ __forceinline__ u32 umin2(u32 a, u32 b) { return a < b ? a : b; }

// ---------------------------------------------------------------- embedding
__global__ __launch_bounds__(256) void embed_k(const int* __restrict__ seq,
                                               const float* __restrict__ emb,
                                               f16* __restrict__ X) {
  int rr = blockIdx.x * 4 + (threadIdx.x >> 6);   // row = s*64 + b
  int lane = threadIdx.x & 63;
  int s = rr >> 6, b = rr & 63;
  int idx = seq[b * NS + s];
  const float* src = emb + (size_t)idx * NE + lane * 8;
  float4 v0 = *(const float4*)(src);
  float4 v1 = *(const float4*)(src + 4);
  f16x8 o;
  o[0] = (f16)v0.x; o[1] = (f16)v0.y; o[2] = (f16)v0.z; o[3] = (f16)v0.w;
  o[4] = (f16)v1.x; o[5] = (f16)v1.y; o[6] = (f16)v1.z; o[7] = (f16)v1.w;
  *(f16x8*)(&X[(size_t)rr * NE + lane * 8]) = o;
}

// ---------------------------------------------------------------- w_ih -> fp16
__global__ __launch_bounds__(256) void wconv(const float* __restrict__ w,
                                             f16* __restrict__ o) {
  int i = (blockIdx.x * 256 + threadIdx.x) * 4;
  float4 v = *(const float4*)(&w[i]);
  f16x4 t = {(f16)v.x, (f16)v.y, (f16)v.z, (f16)v.w};
  *(f16x4*)(&o[i]) = t;
}

// ---------------------------------------------------------------- gx GEMM
// C[m,g] = sum_k X[m,k] * W[g,k] + bih[g];  M=32768 N=3072 K=512
__global__ __launch_bounds__(256) void gemm_gx(const f16* __restrict__ X,
                                               const f16* __restrict__ W,
                                               const float* __restrict__ bih,
                                               f16* __restrict__ GX) {
  __shared__ f16 As[128][40];   // +8 pad: frag-read 2-way banks only
  __shared__ f16 Bs[128][40];
  int tm = blockIdx.x & 255, tn = blockIdx.x >> 8;   // 256 x 24
  int m0 = tm * 128, n0 = tn * 128;
  int tid = threadIdx.x, lane = tid & 63, w = tid >> 6;
  int wm = w & 1, wn = w >> 1;
  f32x4 acc[4][4] = {};
  for (int k0 = 0; k0 < 512; k0 += 32) {
    __syncthreads();
    #pragma unroll
    for (int i = 0; i < 2; i++) {
      int c = tid + i * 256;          // 512 chunks of 16B per operand
      int r = c >> 2, seg = c & 3;
      *(f16x8*)(&As[r][seg * 8]) = *(const f16x8*)(&X[(size_t)(m0 + r) * 512 + k0 + seg * 8]);
      *(f16x8*)(&Bs[r][seg * 8]) = *(const f16x8*)(&W[(size_t)(n0 + r) * 512 + k0 + seg * 8]);
    }
    __syncthreads();
    f16x8 af[4], bf[4];
    int rA = lane & 15, kA = (lane >> 4) * 8;
    #pragma unroll
    for (int i = 0; i < 4; i++) af[i] = *(const f16x8*)(&As[wm * 64 + i * 16 + rA][kA]);
    #pragma unroll
    for (int j = 0; j < 4; j++) bf[j] = *(const f16x8*)(&Bs[wn * 64 + j * 16 + rA][kA]);
    #pragma unroll
    for (int i = 0; i < 4; i++)
      #pragma unroll
      for (int j = 0; j < 4; j++)
        acc[i][j] = __builtin_amdgcn_mfma_f32_16x16x32_f16(af[i], bf[j], acc[i][j], 0, 0, 0);
  }
  int col = lane & 15, rq = lane >> 4;
  #pragma unroll
  for (int j = 0; j < 4; j++) {
    int g = n0 + wn * 64 + j * 16 + col;
    float bias = bih[g];
    #pragma unroll
    for (int i = 0; i < 4; i++) {
      int mbase = m0 + wm * 64 + i * 16 + rq * 4;
      #pragma unroll
      for (int q = 0; q < 4; q++)
        GX[(size_t)(mbase + q) * G3 + g] = (f16)(acc[i][j][q] + bias);
    }
  }
}

// ---------------------------------------------------------------- GRU recurrence
// HT: u32 HT[2][64][1024]; element = (tag << 16) | fp16_bits(h); buffer p holds
// h^(s), s == p (mod 2). FLG[bg][ug] = number of steps WG (bg,ug) has completed
// (stored fire-and-forget AFTER a raw s_barrier that follows the h stores, so
// it statistically arrives after the data; the bulk load re-validates tags, so
// flag/data reordering only costs a rare retry, never correctness).
// Deadlock-freedom: tag s+2 reaches buffer p only after ALL h^(s+1) arrived,
// which requires every same-bg WG to have finished READING h^(s) (stores are
// issued after the final validated read of buffer p in program order).
__global__ __launch_bounds__(256, 1) void gru_rec(const float* __restrict__ whh,
                                                  const float* __restrict__ bhh,
                                                  const f16* __restrict__ GX,
                                                  u32* __restrict__ HT,       // [2][64][1024]
                                                  u32* __restrict__ FLG,      // [4][64]
                                                  float* __restrict__ hlast) { // [64][1024]
  __shared__ f16 wl[48][1032];             // pad 8 -> 2-way bank alias only
  __shared__ float red[2][4][3][16][17];   // step-parity double buffer: 1 sync/step
  const int tid = threadIdx.x, lane = tid & 63, wv = tid >> 6;
  const int bg = blockIdx.x >> 6, ug = blockIdx.x & 63;
  const int brow0 = bg * 16;
  const int q = lane >> 4, r = lane & 15;

  // stage w_hh slice -> LDS fp16. row lr = gate*16+c -> whh[gate*1024 + ug*16 + c]
  for (int lr = 0; lr < 48; lr++) {
    const float* srow = whh + (size_t)((lr >> 4) * NH + ug * 16 + (lr & 15)) * NH;
    float4 v = *(const float4*)(srow + tid * 4);
    f16x4 t = {(f16)v.x, (f16)v.y, (f16)v.z, (f16)v.w};
    *(f16x4*)(&wl[lr][tid * 4]) = t;
  }
  const int b = tid >> 4, u = tid & 15;
  const int ugl = ug * 16 + u;
  const float bh_r = bhh[ugl], bh_z = bhh[NH + ugl], bh_n = bhh[2 * NH + ugl];
  float hown = 0.f;
  __syncthreads();

  #pragma unroll 1
  for (int s = 0; s < NS; s++) {
    // prefetch gx_t (cached loads; latency hides under the flag poll)
    const f16* gxp = GX + ((size_t)s * NB + brow0 + b) * G3 + ugl;
    f16 gr16 = gxp[0], gz16 = gxp[NH], gn16 = gxp[2 * NH];

    // ---- flag gate: all 64 producers of this bg finished step s-1?
    // 64 lanes x 1 dword = 256B/round -- ~60x cheaper than re-polling h data.
    {
      const u32* fp = FLG + bg * 64 + lane;
      for (;;) {
        u32 fv;
        asm volatile("global_load_dword %0, %1, off sc0 sc1\n\t"
                     "s_waitcnt vmcnt(0)"
                     : "=v"(fv) : "v"(fp) : "memory");
        if (__all(fv >= (u32)s)) break;
        __builtin_amdgcn_s_sleep(2);
      }
    }

    // ---- bulk-load h^(s) (once; tags self-validate, retry is rare).
    // wave wv covers k in [wv*256, wv*256+256); lane (q,r): row brow0+r,
    // k = wv*256 + kk*32 + q*8 + {0..7}, kk=0..7.
    u32x4 t[16];
    {
      const u32* hbase = HT + ((size_t)(s & 1) << 16)
                            + ((size_t)(brow0 + r) << 10) + wv * 256 + q * 8;
      const u32 target = (u32)s << 16;
      for (;;) {
        asm volatile(
          "global_load_dwordx4 %0, %[p], off sc0 sc1\n\t"
          "global_load_dwordx4 %1, %[p], off offset:16 sc0 sc1\n\t"
          "global_load_dwordx4 %2, %[p], off offset:128 sc0 sc1\n\t"
          "global_load_dwordx4 %3, %[p], off offset:144 sc0 sc1\n\t"
          "global_load_dwordx4 %4, %[p], off offset:256 sc0 sc1\n\t"
          "global_load_dwordx4 %5, %[p], off offset:272 sc0 sc1\n\t"
          "global_load_dwordx4 %6, %[p], off offset:384 sc0 sc1\n\t"
          "global_load_dwordx4 %7, %[p], off offset:400 sc0 sc1\n\t"
          "global_load_dwordx4 %8, %[p], off offset:512 sc0 sc1\n\t"
          "global_load_dwordx4 %9, %[p], off offset:528 sc0 sc1\n\t"
          "global_load_dwordx4 %10, %[p], off offset:640 sc0 sc1\n\t"
          "global_load_dwordx4 %11, %[p], off offset:656 sc0 sc1\n\t"
          "global_load_dwordx4 %12, %[p], off offset:768 sc0 sc1\n\t"
          "global_load_dwordx4 %13, %[p], off offset:784 sc0 sc1\n\t"
          "global_load_dwordx4 %14, %[p], off offset:896 sc0 sc1\n\t"
          "global_load_dwordx4 %15, %[p], off offset:912 sc0 sc1\n\t"
          "s_waitcnt vmcnt(0)"
          : "=&v"(t[0]), "=&v"(t[1]), "=&v"(t[2]), "=&v"(t[3]),
            "=&v"(t[4]), "=&v"(t[5]), "=&v"(t[6]), "=&v"(t[7]),
            "=&v"(t[8]), "=&v"(t[9]), "=&v"(t[10]), "=&v"(t[11]),
            "=&v"(t[12]), "=&v"(t[13]), "=&v"(t[14]), "=&v"(t[15])
          : [p] "v"(hbase)
          : "memory");
        u32 mn = 0xFFFFFFFFu;
        #pragma unroll
        for (int i = 0; i < 16; i++) {
          u32x4 v = t[i];
          mn = umin2(mn, umin2(umin2(v[0], v[1]), umin2(v[2], v[3])));
        }
        if (__all(mn >= target)) break;
        __builtin_amdgcn_s_sleep(2);
      }
    }
    // ---- repack {tag,h} dwords -> f16x8 A-fragments (v_perm)
    f16x8 af[8];
    #pragma unroll
    for (int kk = 0; kk < 8; kk++) {
      u32x4 a = t[2 * kk], c = t[2 * kk + 1];
      u32x4 pk;
      pk[0] = __builtin_amdgcn_perm(a[1], a[0], 0x05040100);
      pk[1] = __builtin_amdgcn_perm(a[3], a[2], 0x05040100);
      pk[2] = __builtin_amdgcn_perm(c[1], c[0], 0x05040100);
      pk[3] = __builtin_amdgcn_perm(c[3], c[2], 0x05040100);
      af[kk] = __builtin_bit_cast(f16x8, pk);
    }
    f32x4 acc[3] = {};
    #pragma unroll
    for (int kk = 0; kk < 8; kk++) {
      const int kof = wv * 256 + kk * 32 + q * 8;
      #pragma unroll
      for (int n = 0; n < 3; n++) {
        f16x8 bfrag = *(const f16x8*)(&wl[n * 16 + r][kof]);
        acc[n] = __builtin_amdgcn_mfma_f32_16x16x32_f16(af[kk], bfrag, acc[n], 0, 0, 0);
      }
    }
    const int rp = s & 1;
    #pragma unroll
    for (int n = 0; n < 3; n++)
      #pragma unroll
      for (int q2 = 0; q2 < 4; q2++)
        red[rp][wv][n][q * 4 + q2][r] = acc[n][q2];
    __syncthreads();                      // the only draining barrier per step
    float ghr = bh_r, ghz = bh_z, ghn = bh_n;
    #pragma unroll
    for (int w2 = 0; w2 < 4; w2++) {
      ghr += red[rp][w2][0][b][u];
      ghz += red[rp][w2][1][b][u];
      ghn += red[rp][w2][2][b][u];
    }
    const float xr = (float)gr16, xz = (float)gz16, xn = (float)gn16;
    const float rg = 1.f / (1.f + __expf(-(xr + ghr)));
    const float z = 1.f / (1.f + __expf(-(xz + ghz)));
    float nv;
    {
      const float a = xn + rg * ghn;
      const float tt = __expf(-2.f * fabsf(a));
      nv = (1.f - tt) / (1.f + tt);
      nv = a < 0.f ? -nv : nv;
    }
    hown = (1.f - z) * nv + z * hown;
    // fire-and-forget write-through of packed {tag=s+1, h}
    {
      u32* hdst = HT + ((size_t)((s + 1) & 1) << 16) + ((size_t)(brow0 + b) << 10) + ugl;
      union { f16 h; unsigned short us; } cv;
      cv.h = (f16)hown;
      u32 hv = ((u32)(s + 1) << 16) | (u32)cv.us;
      asm volatile("global_store_dword %0, %1, off sc0 sc1"
                   :: "v"(hdst), "v"(hv) : "memory");
    }
    if (s == NS - 1) hlast[(size_t)(brow0 + b) * NH + ugl] = hown;
    // raw barrier (NO vmcnt drain): all waves' h stores are issued; the flag
    // store issued after this is queue-biased to arrive after the data.
    __builtin_amdgcn_s_barrier();
    if (tid == 0) {
      u32* fdst = FLG + bg * 64 + ug;
      u32 fv = (u32)(s + 1);
      asm volatile("global_store_dword %0, %1, off sc0 sc1"
                   :: "v"(fdst), "v"(fv) : "memory");
    }
  }
}

// ---------------------------------------------------------------- FC head
__global__ __launch_bounds__(64) void fc_k(const float* __restrict__ hl,
                                           const float* __restrict__ fw,
                                           const float* __restrict__ fb,
                                           float* __restrict__ out) {
  int b = blockIdx.x, t = threadIdx.x;
  float a0 = 0.f, a1 = 0.f;
  for (int k = t; k < NH; k += 64) {
    float h = hl[b * NH + k];
    a0 += h * fw[k];
    a1 += h * fw[NH + k];
  }
  #pragma unroll
  for (int off = 32; off; off >>= 1) {
    a0 += __shfl_down(a0, off);
    a1 += __shfl_down(a1, off);
  }
  if (t == 0) {
    out[b * 2 + 0] = a0 + fb[0];
    out[b * 2 + 1] = a1 + fb[1];
  }
}

// ---------------------------------------------------------------- launcher
extern "C" void kernel_launch(void* const* d_in, const int* in_sizes, int n_in,
                              void* d_out, int out_size, void* d_ws, size_t ws_size,
                              hipStream_t stream) {
  const int*   seq = (const int*)d_in[0];
  const float* emb = (const float*)d_in[1];
  const float* wih = (const float*)d_in[2];
  const float* whh = (const float*)d_in[3];
  const float* bih = (const float*)d_in[4];
  const float* bhh = (const float*)d_in[5];
  const float* fcw = (const float*)d_in[6];
  const float* fcb = (const float*)d_in[7];
  float* out = (float*)d_out;

  char* ws = (char*)d_ws;
  size_t off = 0;
  f16* X = (f16*)(ws + off);   off += (size_t)NS * NB * NE * 2;   // 33.6 MB
  f16* W16 = (f16*)(ws + off); off += (size_t)G3 * NE * 2;        // 3.1 MB
  f16* GX = (f16*)(ws + off);  off += (size_t)NS * NB * G3 * 2;   // 201 MB
  u32* HT = (u32*)(ws + off);  off += (size_t)2 * NB * NH * 4;    // 512 KB
  u32* FLG = (u32*)(ws + off); off += 4 * 64 * 4;                 // 1 KB (after HT!)
  float* HL = (float*)(ws + off); off += (size_t)NB * NH * 4;     // 256 KB
  if (ws_size < off) return;  // insufficient workspace -> fail visibly, no OOB

  // MUST zero HT+FLG every call: harness poisons ws with 0xAA, which would
  // read as fresh tags/flags with garbage h. (HT and FLG are contiguous.)
  hipMemsetAsync(HT, 0, (size_t)2 * NB * NH * 4 + 4 * 64 * 4, stream);

  embed_k<<<(NS * NB) / 4, 256, 0, stream>>>(seq, emb, X);
  wconv<<<(G3 * NE) / 1024, 256, 0, stream>>>(wih, W16);
  gemm_gx<<<256 * 24, 256, 0, stream>>>(X, W16, bih, GX);
  gru_rec<<<256, 256, 0, stream>>>(whh, bhh, GX, HT, FLG, HL);
  fc_k<<<NB, 64, 0, stream>>>(HL, fcw, fcb, out);
}

// Round 6
// 2168.385 us; speedup vs baseline: 1.7180x; 1.7180x over previous
//
#include <hip/hip_runtime.h>
#include <stdint.h>
#include <stddef.h>

// ---------------------------------------------------------------------------
// Discriminator: embedding [64,512] -> GRU(512->1024, 512 steps) -> FC(1024->2)
//   k1 embed_k : gather emb rows -> X fp16 [S*B, 512]   (row = s*64+b)
//   k2 wconv   : w_ih fp32 -> fp16
//   k3 gemm_gx : GX = X @ w_ih^T + b_ih  -> fp16 [S*B, 3072]  (MFMA 128x128 tile)
//   k4 gru_rec : persistent 256-WG kernel, 4 batch-groups x 64 unit-groups,
//                w_hh slice LDS-resident fp16. R2-proven sync structure:
//                ack'd sc0sc1 fp16 h stores -> relaxed per-bg counter bump;
//                consumers: wave-autonomous counter poll -> ONE bulk load.
//   k5 fc_k    : logits = h_last @ fc_w^T + fc_b -> d_out fp32 [64,2]
// ---------------------------------------------------------------------------

typedef _Float16 f16;
typedef _Float16 f16x4 __attribute__((ext_vector_type(4)));
typedef _Float16 f16x8 __attribute__((ext_vector_type(8)));
typedef float f32x4 __attribute__((ext_vector_type(4)));
typedef unsigned int u32;

#define NB 64      // batch
#define NS 512     // seq len
#define NE 512     // embedding dim
#define NH 1024    // hidden
#define G3 3072    // 3*NH

// ---------------------------------------------------------------- embedding
__global__ __launch_bounds__(256) void embed_k(const int* __restrict__ seq,
                                               const float* __restrict__ emb,
                                               f16* __restrict__ X) {
  int rr = blockIdx.x * 4 + (threadIdx.x >> 6);   // row = s*64 + b
  int lane = threadIdx.x & 63;
  int s = rr >> 6, b = rr & 63;
  int idx = seq[b * NS + s];
  const float* src = emb + (size_t)idx * NE + lane * 8;
  float4 v0 = *(const float4*)(src);
  float4 v1 = *(const float4*)(src + 4);
  f16x8 o;
  o[0] = (f16)v0.x; o[1] = (f16)v0.y; o[2] = (f16)v0.z; o[3] = (f16)v0.w;
  o[4] = (f16)v1.x; o[5] = (f16)v1.y; o[6] = (f16)v1.z; o[7] = (f16)v1.w;
  *(f16x8*)(&X[(size_t)rr * NE + lane * 8]) = o;
}

// ---------------------------------------------------------------- w_ih -> fp16
__global__ __launch_bounds__(256) void wconv(const float* __restrict__ w,
                                             f16* __restrict__ o) {
  int i = (blockIdx.x * 256 + threadIdx.x) * 4;
  float4 v = *(const float4*)(&w[i]);
  f16x4 t = {(f16)v.x, (f16)v.y, (f16)v.z, (f16)v.w};
  *(f16x4*)(&o[i]) = t;
}

// ---------------------------------------------------------------- gx GEMM
// C[m,g] = sum_k X[m,k] * W[g,k] + bih[g];  M=32768 N=3072 K=512
__global__ __launch_bounds__(256) void gemm_gx(const f16* __restrict__ X,
                                               const f16* __restrict__ W,
                                               const float* __restrict__ bih,
                                               f16* __restrict__ GX) {
  __shared__ f16 As[128][40];   // +8 pad: frag-read 2-way banks only
  __shared__ f16 Bs[128][40];
  int tm = blockIdx.x & 255, tn = blockIdx.x >> 8;   // 256 x 24
  int m0 = tm * 128, n0 = tn * 128;
  int tid = threadIdx.x, lane = tid & 63, w = tid >> 6;
  int wm = w & 1, wn = w >> 1;
  f32x4 acc[4][4] = {};
  for (int k0 = 0; k0 < 512; k0 += 32) {
    __syncthreads();
    #pragma unroll
    for (int i = 0; i < 2; i++) {
      int c = tid + i * 256;          // 512 chunks of 16B per operand
      int r = c >> 2, seg = c & 3;
      *(f16x8*)(&As[r][seg * 8]) = *(const f16x8*)(&X[(size_t)(m0 + r) * 512 + k0 + seg * 8]);
      *(f16x8*)(&Bs[r][seg * 8]) = *(const f16x8*)(&W[(size_t)(n0 + r) * 512 + k0 + seg * 8]);
    }
    __syncthreads();
    f16x8 af[4], bf[4];
    int rA = lane & 15, kA = (lane >> 4) * 8;
    #pragma unroll
    for (int i = 0; i < 4; i++) af[i] = *(const f16x8*)(&As[wm * 64 + i * 16 + rA][kA]);
    #pragma unroll
    for (int j = 0; j < 4; j++) bf[j] = *(const f16x8*)(&Bs[wn * 64 + j * 16 + rA][kA]);
    #pragma unroll
    for (int i = 0; i < 4; i++)
      #pragma unroll
      for (int j = 0; j < 4; j++)
        acc[i][j] = __builtin_amdgcn_mfma_f32_16x16x32_f16(af[i], bf[j], acc[i][j], 0, 0, 0);
  }
  int col = lane & 15, rq = lane >> 4;
  #pragma unroll
  for (int j = 0; j < 4; j++) {
    int g = n0 + wn * 64 + j * 16 + col;
    float bias = bih[g];
    #pragma unroll
    for (int i = 0; i < 4; i++) {
      int mbase = m0 + wm * 64 + i * 16 + rq * 4;
      #pragma unroll
      for (int q = 0; q < 4; q++)
        GX[(size_t)(mbase + q) * G3 + g] = (f16)(acc[i][j][q] + bias);
    }
  }
}

// ---------------------------------------------------------------- GRU recurrence
// HB: f16 [2][64][1024], buffer p holds h^(s) for s == p (mod 2).
// CNT[bg]: relaxed agent atomic counter; value 64*(s+1) <=> all 64 WGs of bg
// completed step s AND their h stores are COMPLETE at the coherence point
// (each thread acks its own sc0sc1 store with vmcnt(0) before the bump-sync).
// Consumers therefore need exactly ONE bulk load per step -- no tags/retries.
// Buffer WAR safety: h^(s+2) overwrites buffer p only after cnt>=64(s+1),
// which requires every same-bg WG to have bulk-READ h^(s) (read precedes its
// bump in program order).
__global__ __launch_bounds__(256, 1) void gru_rec(const float* __restrict__ whh,
                                                  const float* __restrict__ bhh,
                                                  const f16* __restrict__ GX,
                                                  f16* __restrict__ HB,       // [2][64][1024]
                                                  u32* __restrict__ CNT,      // [4*32]
                                                  float* __restrict__ hlast) { // [64][1024]
  __shared__ f16 wl[48][1032];          // pad 8 -> 2-way bank alias only
  __shared__ float red[4][3][16][17];   // pad 17 -> conflict-free reduce
  const int tid = threadIdx.x, lane = tid & 63, wv = tid >> 6;
  const int bg = blockIdx.x >> 6, ug = blockIdx.x & 63;
  const int brow0 = bg * 16;
  const int q = lane >> 4, r = lane & 15;

  // stage w_hh slice -> LDS fp16. row lr = gate*16+c -> whh[gate*1024 + ug*16 + c]
  for (int lr = 0; lr < 48; lr++) {
    const float* srow = whh + (size_t)((lr >> 4) * NH + ug * 16 + (lr & 15)) * NH;
    float4 v = *(const float4*)(srow + tid * 4);
    f16x4 t = {(f16)v.x, (f16)v.y, (f16)v.z, (f16)v.w};
    *(f16x4*)(&wl[lr][tid * 4]) = t;
  }
  const int b = tid >> 4, u = tid & 15;
  const int ugl = ug * 16 + u;
  const float bh_r = bhh[ugl], bh_z = bhh[NH + ugl], bh_n = bhh[2 * NH + ugl];
  float hown = 0.f;
  const u32* myc = CNT + bg * 32;       // 128B-separated per-bg counters
  __syncthreads();

  #pragma unroll 1
  for (int s = 0; s < NS; s++) {
    // prefetch gx_t (plain cached loads; latency hides under the counter poll)
    const f16* gxp = GX + ((size_t)s * NB + brow0 + b) * G3 + ugl;
    f16 gr16 = gxp[0], gz16 = gxp[NH], gn16 = gxp[2 * NH];

    // ---- wave-autonomous counter poll: all lanes read the same dword
    // (1 broadcast request/round); wave-uniform exit, no block barrier --
    // each wave fires its bulk load the moment IT sees the count.
    {
      const u32 target = 64u * (u32)s;
      for (;;) {
        u32 v;
        asm volatile("global_load_dword %0, %1, off sc0 sc1\n\t"
                     "s_waitcnt vmcnt(0)"
                     : "=v"(v) : "v"(myc) : "memory");
        if (__all(v >= target)) break;
        __builtin_amdgcn_s_sleep(1);
      }
    }

    // ---- single bulk load of h^(s) (fp16, lands directly as MFMA A-frags).
    // wave wv covers k in [wv*256, wv*256+256); lane (q,r): row brow0+r,
    // k = wv*256 + kk*32 + q*8 + {0..7}, kk=0..7.  8 x dwordx4 = 32KB/WG.
    f16x8 af[8];
    {
      const f16* hrow = HB + ((size_t)(s & 1) << 16)
                           + ((size_t)(brow0 + r) << 10) + wv * 256 + q * 8;
      asm volatile(
        "global_load_dwordx4 %0, %[p], off sc0 sc1\n\t"
        "global_load_dwordx4 %1, %[p], off offset:64 sc0 sc1\n\t"
        "global_load_dwordx4 %2, %[p], off offset:128 sc0 sc1\n\t"
        "global_load_dwordx4 %3, %[p], off offset:192 sc0 sc1\n\t"
        "global_load_dwordx4 %4, %[p], off offset:256 sc0 sc1\n\t"
        "global_load_dwordx4 %5, %[p], off offset:320 sc0 sc1\n\t"
        "global_load_dwordx4 %6, %[p], off offset:384 sc0 sc1\n\t"
        "global_load_dwordx4 %7, %[p], off offset:448 sc0 sc1\n\t"
        "s_waitcnt vmcnt(0)"
        : "=&v"(af[0]), "=&v"(af[1]), "=&v"(af[2]), "=&v"(af[3]),
          "=&v"(af[4]), "=&v"(af[5]), "=&v"(af[6]), "=&v"(af[7])
        : [p] "v"(hrow)
        : "memory");
      __builtin_amdgcn_sched_barrier(0);  // rule #18: keep MFMA after the waitcnt
    }
    f32x4 acc[3] = {};
    #pragma unroll
    for (int kk = 0; kk < 8; kk++) {
      const int kof = wv * 256 + kk * 32 + q * 8;
      #pragma unroll
      for (int n = 0; n < 3; n++) {
        f16x8 bfrag = *(const f16x8*)(&wl[n * 16 + r][kof]);
        acc[n] = __builtin_amdgcn_mfma_f32_16x16x32_f16(af[kk], bfrag, acc[n], 0, 0, 0);
      }
    }
    #pragma unroll
    for (int n = 0; n < 3; n++)
      #pragma unroll
      for (int q2 = 0; q2 < 4; q2++)
        red[wv][n][q * 4 + q2][r] = acc[n][q2];
    __syncthreads();                      // sync #1: red ready
    float ghr = bh_r, ghz = bh_z, ghn = bh_n;
    #pragma unroll
    for (int w2 = 0; w2 < 4; w2++) {
      ghr += red[w2][0][b][u];
      ghz += red[w2][1][b][u];
      ghn += red[w2][2][b][u];
    }
    const float xr = (float)gr16, xz = (float)gz16, xn = (float)gn16;
    const float rg = 1.f / (1.f + __expf(-(xr + ghr)));
    const float z = 1.f / (1.f + __expf(-(xz + ghz)));
    float nv;
    {
      const float a = xn + rg * ghn;
      const float tt = __expf(-2.f * fabsf(a));
      nv = (1.f - tt) / (1.f + tt);
      nv = a < 0.f ? -nv : nv;
    }
    hown = (1.f - z) * nv + z * hown;
    // write-through h store, then ACK it (vmcnt(0)) -- this is what makes the
    // consumer's single bulk load sufficient (no tags, no retries).
    {
      f16* hdst = HB + ((size_t)((s + 1) & 1) << 16) + ((size_t)(brow0 + b) << 10) + ugl;
      union { f16 h; unsigned short us; } cv;
      cv.h = (f16)hown;
      u32 hv = (u32)cv.us;
      asm volatile("global_store_short %0, %1, off sc0 sc1"
                   :: "v"(hdst), "v"(hv) : "memory");
    }
    if (s == NS - 1) hlast[(size_t)(brow0 + b) * NH + ugl] = hown;
    asm volatile("s_waitcnt vmcnt(0)" ::: "memory");  // own store complete at IF$
    __syncthreads();                      // sync #2: ALL threads' stores acked;
                                          // also WAR-guards red[] (our own bump
                                          // below is included in next target)
    if (tid == 0)
      __hip_atomic_fetch_add((u32*)myc, 1u, __ATOMIC_RELAXED, __HIP_MEMORY_SCOPE_AGENT);
  }
}

// ---------------------------------------------------------------- FC head
__global__ __launch_bounds__(64) void fc_k(const float* __restrict__ hl,
                                           const float* __restrict__ fw,
                                           const float* __restrict__ fb,
                                           float* __restrict__ out) {
  int b = blockIdx.x, t = threadIdx.x;
  float a0 = 0.f, a1 = 0.f;
  for (int k = t; k < NH; k += 64) {
    float h = hl[b * NH + k];
    a0 += h * fw[k];
    a1 += h * fw[NH + k];
  }
  #pragma unroll
  for (int off = 32; off; off >>= 1) {
    a0 += __shfl_down(a0, off);
    a1 += __shfl_down(a1, off);
  }
  if (t == 0) {
    out[b * 2 + 0] = a0 + fb[0];
    out[b * 2 + 1] = a1 + fb[1];
  }
}

// ---------------------------------------------------------------- launcher
extern "C" void kernel_launch(void* const* d_in, const int* in_sizes, int n_in,
                              void* d_out, int out_size, void* d_ws, size_t ws_size,
                              hipStream_t stream) {
  const int*   seq = (const int*)d_in[0];
  const float* emb = (const float*)d_in[1];
  const float* wih = (const float*)d_in[2];
  const float* whh = (const float*)d_in[3];
  const float* bih = (const float*)d_in[4];
  const float* bhh = (const float*)d_in[5];
  const float* fcw = (const float*)d_in[6];
  const float* fcb = (const float*)d_in[7];
  float* out = (float*)d_out;

  char* ws = (char*)d_ws;
  size_t off = 0;
  f16* X = (f16*)(ws + off);   off += (size_t)NS * NB * NE * 2;   // 33.6 MB
  f16* W16 = (f16*)(ws + off); off += (size_t)G3 * NE * 2;        // 3.1 MB
  f16* GX = (f16*)(ws + off);  off += (size_t)NS * NB * G3 * 2;   // 201 MB
  f16* HB = (f16*)(ws + off);  off += (size_t)2 * NB * NH * 2;    // 256 KB
  u32* CNT = (u32*)(ws + off); off += 4 * 32 * 4;                 // 512 B
  float* HL = (float*)(ws + off); off += (size_t)NB * NH * 4;     // 256 KB
  if (ws_size < off) return;  // insufficient workspace -> fail visibly, no OOB

  // Zero h0 (parity-0 buffer) and counters every call (ws is 0xAA-poisoned).
  hipMemsetAsync(HB, 0, (size_t)2 * NB * NH * 2 + 4 * 32 * 4, stream);

  embed_k<<<(NS * NB) / 4, 256, 0, stream>>>(seq, emb, X);
  wconv<<<(G3 * NE) / 1024, 256, 0, stream>>>(wih, W16);
  gemm_gx<<<256 * 24, 256, 0, stream>>>(X, W16, bih, GX);
  gru_rec<<<256, 256, 0, stream>>>(whh, bhh, GX, HB, CNT, HL);
  fc_k<<<NB, 64, 0, stream>>>(HL, fcw, fcb, out);
}